// Round 1
// baseline (259.826 us; speedup 1.0000x reference)
//
#include <hip/hip_runtime.h>

#define A_N 1024
#define T_N 256
#define CS 384
#define CZ 128
#define CA 128
#define CP 16
#define LN_EPS 1e-5f

// --- recover tok[a] from the one-hot atom->token matrix ---
__global__ void tok_kernel(const float* __restrict__ a2t, int* __restrict__ tok) {
    int a = blockIdx.x;
    int t = threadIdx.x;           // 256 threads = T_N
    if (a2t[a * T_N + t] > 0.5f) tok[a] = t;
}

// --- Ys[t,:] = LN(s_trunk[t,:]) @ W_s   (256 rows, c_s=384 -> c_atom=128) ---
__global__ void s_phase_kernel(const float* __restrict__ s_trunk,
                               const float* __restrict__ g,
                               const float* __restrict__ b,
                               const float* __restrict__ W_s,
                               float* __restrict__ Ys) {
    int t = blockIdx.x;
    int tid = threadIdx.x;  // 0..127
    __shared__ float xs[CS];
    __shared__ float rs[128], rq[128];
    float sum = 0.f, sq = 0.f;
    for (int j = 0; j < 3; ++j) {
        float v = s_trunk[t * CS + j * 128 + tid];
        xs[j * 128 + tid] = v;
        sum += v; sq += v * v;
    }
    rs[tid] = sum; rq[tid] = sq;
    __syncthreads();
    for (int s = 64; s > 0; s >>= 1) {
        if (tid < s) { rs[tid] += rs[tid + s]; rq[tid] += rq[tid + s]; }
        __syncthreads();
    }
    float m = rs[0] * (1.f / CS);
    float var = rq[0] * (1.f / CS) - m * m;
    float rstd = rsqrtf(var + LN_EPS);
    float acc = 0.f;
    for (int k = 0; k < CS; ++k) {
        float zn = (xs[k] - m) * rstd * g[k] + b[k];
        acc = fmaf(zn, W_s[k * CA + tid], acc);
    }
    Ys[t * CA + tid] = acc;
}

// --- Yz[t,u,:] = LN(zij[t,u,:]) @ W_z   (65536 rows, c_z=128 -> c_pair=16) ---
// one wave (64 threads) per row
__global__ void z_phase_kernel(const float* __restrict__ zij,
                               const float* __restrict__ g,
                               const float* __restrict__ b,
                               const float* __restrict__ W_z,
                               float* __restrict__ Yz) {
    int row = blockIdx.x;          // t*T_N + u
    int lane = threadIdx.x;        // 0..63
    float2 z2 = ((const float2*)(zij + (size_t)row * CZ))[lane];
    float sum = z2.x + z2.y;
    float sq  = z2.x * z2.x + z2.y * z2.y;
    for (int off = 32; off > 0; off >>= 1) {
        sum += __shfl_down(sum, off);
        sq  += __shfl_down(sq,  off);
    }
    sum = __shfl(sum, 0);
    sq  = __shfl(sq, 0);
    float m = sum * (1.f / CZ);
    float var = sq * (1.f / CZ) - m * m;
    float rstd = rsqrtf(var + LN_EPS);
    __shared__ float zn[CZ];
    zn[2 * lane]     = (z2.x - m) * rstd * g[2 * lane]     + b[2 * lane];
    zn[2 * lane + 1] = (z2.y - m) * rstd * g[2 * lane + 1] + b[2 * lane + 1];
    __syncthreads();
    if (lane < CP) {
        float acc = 0.f;
        for (int k = 0; k < CZ; ++k)
            acc = fmaf(zn[k], W_z[k * CP + lane], acc);
        Yz[(size_t)row * CP + lane] = acc;
    }
}

// --- cl_out[a,c] = cl[a,c] + Ys[tok[a],c] ---
__global__ void cl_final_kernel(const float* __restrict__ cl,
                                const float* __restrict__ Ys,
                                const int* __restrict__ tok,
                                float* __restrict__ out) {
    int i = blockIdx.x * blockDim.x + threadIdx.x;  // 0 .. A_N*CA
    int a = i >> 7;
    int c = i & 127;
    out[i] = cl[i] + Ys[tok[a] * CA + c];
}

// --- plm_out[a,b,:] = plm[a,b,:] + Yz[tok[a],tok[b],:]  (float4-vectorized) ---
__global__ void plm_final_kernel(const float* __restrict__ plm,
                                 const float* __restrict__ Yz,
                                 const int* __restrict__ tok,
                                 float* __restrict__ out) {
    int i = blockIdx.x * blockDim.x + threadIdx.x;  // float4 index, 0 .. 4M
    int p  = i >> 2;       // pair index a*1024+b
    int c4 = i & 3;        // which float4 within the 16 channels
    int a = p >> 10;
    int b = p & 1023;
    int ta = tok[a];
    int tb = tok[b];
    float4 pv = ((const float4*)plm)[i];
    float4 yv = ((const float4*)(Yz + (size_t)(ta * T_N + tb) * CP))[c4];
    float4 o;
    o.x = pv.x + yv.x; o.y = pv.y + yv.y;
    o.z = pv.z + yv.z; o.w = pv.w + yv.w;
    ((float4*)out)[i] = o;
}

// --- ql_out[a,c] = ql[a,c] + rl[a,:] @ W_r[:,c] ---
__global__ void ql_final_kernel(const float* __restrict__ ql,
                                const float* __restrict__ rl,
                                const float* __restrict__ W_r,
                                float* __restrict__ out) {
    int i = blockIdx.x * blockDim.x + threadIdx.x;  // 0 .. A_N*CA
    int a = i >> 7;
    int c = i & 127;
    float r0 = rl[a * 3 + 0], r1 = rl[a * 3 + 1], r2 = rl[a * 3 + 2];
    out[i] = ql[i] + r0 * W_r[c] + r1 * W_r[CA + c] + r2 * W_r[2 * CA + c];
}

extern "C" void kernel_launch(void* const* d_in, const int* in_sizes, int n_in,
                              void* d_out, int out_size, void* d_ws, size_t ws_size,
                              hipStream_t stream) {
    const float* a2t     = (const float*)d_in[0];
    const float* cl      = (const float*)d_in[1];
    const float* plm     = (const float*)d_in[2];
    const float* ql      = (const float*)d_in[3];
    const float* s_trunk = (const float*)d_in[4];
    const float* zij     = (const float*)d_in[5];
    const float* rl      = (const float*)d_in[6];
    const float* ln_s_g  = (const float*)d_in[7];
    const float* ln_s_b  = (const float*)d_in[8];
    const float* W_s     = (const float*)d_in[9];
    const float* ln_z_g  = (const float*)d_in[10];
    const float* ln_z_b  = (const float*)d_in[11];
    const float* W_z     = (const float*)d_in[12];
    const float* W_r     = (const float*)d_in[13];

    // workspace layout
    int*   tok = (int*)d_ws;                                   // 1024 ints
    float* Ys  = (float*)((char*)d_ws + 4096);                 // 256*128 floats
    float* Yz  = (float*)((char*)d_ws + 4096 + 131072 * 4);    // 65536*16 floats

    // output layout: cl [1024*128], plm [1024*1024*16], ql [1024*128]
    float* out_cl  = (float*)d_out;
    float* out_plm = out_cl + A_N * CA;
    float* out_ql  = out_plm + (size_t)A_N * A_N * CP;

    tok_kernel<<<A_N, T_N, 0, stream>>>(a2t, tok);
    s_phase_kernel<<<T_N, 128, 0, stream>>>(s_trunk, ln_s_g, ln_s_b, W_s, Ys);
    z_phase_kernel<<<T_N * T_N, 64, 0, stream>>>(zij, ln_z_g, ln_z_b, W_z, Yz);
    cl_final_kernel<<<(A_N * CA) / 256, 256, 0, stream>>>(cl, Ys, tok, out_cl);
    plm_final_kernel<<<((size_t)A_N * A_N * CP / 4) / 256, 256, 0, stream>>>(plm, Yz, tok, out_plm);
    ql_final_kernel<<<(A_N * CA) / 256, 256, 0, stream>>>(ql, rl, W_r, out_ql);
}

// Round 2
// 205.941 us; speedup vs baseline: 1.2617x; 1.2617x over previous
//
#include <hip/hip_runtime.h>

#define A_N 1024
#define T_N 256
#define CS 384
#define CZ 128
#define CA 128
#define CP 16
#define LN_EPS 1e-5f

#define ZROWS 64     // rows per z-phase block
#define ZPAD 132     // padded LDS row stride (floats), keeps 16B align, breaks bank aliasing

// --- recover tok[a] from the one-hot atom->token matrix ---
__global__ void tok_kernel(const float* __restrict__ a2t, int* __restrict__ tok) {
    int a = blockIdx.x;
    int t = threadIdx.x;           // 256 threads = T_N
    if (a2t[a * T_N + t] > 0.5f) tok[a] = t;
}

// --- Gw[j] = sum_k g[k]*W_z[k,j], Bw[j] = sum_k b[k]*W_z[k,j] ---
__global__ void prep_gwbw_kernel(const float* __restrict__ g,
                                 const float* __restrict__ b,
                                 const float* __restrict__ W_z,
                                 float* __restrict__ Gw,
                                 float* __restrict__ Bw) {
    __shared__ float pg[16][16], pb[16][16];
    int t = threadIdx.x;          // 256
    int j = t & 15, seg = t >> 4;
    float sg = 0.f, sb = 0.f;
    #pragma unroll
    for (int i = 0; i < 8; ++i) {
        int k = seg * 8 + i;
        float w = W_z[k * CP + j];
        sg = fmaf(g[k], w, sg);
        sb = fmaf(b[k], w, sb);
    }
    pg[seg][j] = sg; pb[seg][j] = sb;
    __syncthreads();
    if (t < 16) {
        float a = 0.f, c = 0.f;
        #pragma unroll
        for (int s = 0; s < 16; ++s) { a += pg[s][t]; c += pb[s][t]; }
        Gw[t] = a; Bw[t] = c;
    }
}

// --- Ys[t,:] = LN(s_trunk[t,:]) @ W_s   (256 rows, c_s=384 -> c_atom=128) ---
__global__ void s_phase_kernel(const float* __restrict__ s_trunk,
                               const float* __restrict__ g,
                               const float* __restrict__ b,
                               const float* __restrict__ W_s,
                               float* __restrict__ Ys) {
    int t = blockIdx.x;
    int tid = threadIdx.x;  // 0..127
    __shared__ float xs[CS];
    __shared__ float rs[128], rq[128];
    float sum = 0.f, sq = 0.f;
    for (int j = 0; j < 3; ++j) {
        float v = s_trunk[t * CS + j * 128 + tid];
        xs[j * 128 + tid] = v;
        sum += v; sq += v * v;
    }
    rs[tid] = sum; rq[tid] = sq;
    __syncthreads();
    for (int s = 64; s > 0; s >>= 1) {
        if (tid < s) { rs[tid] += rs[tid + s]; rq[tid] += rq[tid + s]; }
        __syncthreads();
    }
    float m = rs[0] * (1.f / CS);
    float var = rq[0] * (1.f / CS) - m * m;
    float rstd = rsqrtf(var + LN_EPS);
    float acc = 0.f;
    for (int k = 0; k < CS; ++k) {
        float zn = (xs[k] - m) * rstd * g[k] + b[k];
        acc = fmaf(zn, W_s[k * CA + tid], acc);
    }
    Ys[t * CA + tid] = acc;
}

// --- Yz[row,:] = LN(zij[row,:]) @ W_z, 64 rows per 256-thread block ---
// LN folded into matmul: y[j] = rstd*(x@(g*W)[:,j] - m*Gw[j]) + Bw[j]
__global__ __launch_bounds__(256) void z_phase2_kernel(
        const float* __restrict__ zij,
        const float* __restrict__ g,
        const float* __restrict__ W_z,
        const float* __restrict__ Gw,
        const float* __restrict__ Bw,
        float* __restrict__ Yz) {
    __shared__ float xs[ZROWS * ZPAD];     // 64 x 128 tile, padded
    __shared__ float wgt[CP * ZPAD];       // Wg transposed: wgt[j][k] = g[k]*W[k][j]
    __shared__ float2 parts[ZROWS][4];     // per-row partial (sum, sumsq)
    __shared__ float msh[ZROWS], rsh[ZROWS];

    int t = threadIdx.x;
    size_t base = (size_t)blockIdx.x * ZROWS * CZ;   // float offset into zij

    // stage x tile: 64 rows x 32 float4, coalesced
    const float4* zv = (const float4*)(zij + base);
    #pragma unroll
    for (int n = 0; n < 8; ++n) {
        int idx = n * 256 + t;            // float4 index in tile
        int r = idx >> 5, c = idx & 31;
        float4 v = zv[idx];
        *(float4*)&xs[r * ZPAD + c * 4] = v;
    }
    // stage Wg transposed
    #pragma unroll
    for (int n = 0; n < 8; ++n) {
        int idx = n * 256 + t;            // 0..2047 over W_z [128,16]
        int k = idx >> 4, j = idx & 15;
        wgt[j * ZPAD + k] = g[k] * W_z[idx];
    }
    __syncthreads();

    // per-row stats: 4 threads per row, 32 elements each
    {
        int r = t >> 2, q = t & 3;
        const float* row = &xs[r * ZPAD + q * 32];
        float s = 0.f, ss = 0.f;
        #pragma unroll
        for (int i = 0; i < 8; ++i) {
            float4 v = *(const float4*)&row[i * 4];
            s += v.x + v.y + v.z + v.w;
            ss += v.x * v.x + v.y * v.y + v.z * v.z + v.w * v.w;
        }
        parts[r][q] = make_float2(s, ss);
    }
    __syncthreads();
    if (t < ZROWS) {
        float s = 0.f, ss = 0.f;
        #pragma unroll
        for (int q = 0; q < 4; ++q) { float2 p = parts[t][q]; s += p.x; ss += p.y; }
        float m = s * (1.f / CZ);
        float var = ss * (1.f / CZ) - m * m;
        msh[t] = m;
        rsh[t] = rsqrtf(var + LN_EPS);
    }
    __syncthreads();

    // matmul: thread (rg, j) computes 4 rows x 1 output
    int j = t & 15, rg = t >> 4;           // rg 0..15
    float acc[4] = {0.f, 0.f, 0.f, 0.f};
    const float* wrow = &wgt[j * ZPAD];
    #pragma unroll 4
    for (int k4 = 0; k4 < 32; ++k4) {
        float4 w = *(const float4*)&wrow[k4 * 4];
        #pragma unroll
        for (int rr = 0; rr < 4; ++rr) {
            float4 x = *(const float4*)&xs[(rg * 4 + rr) * ZPAD + k4 * 4];
            acc[rr] = fmaf(x.x, w.x, acc[rr]);
            acc[rr] = fmaf(x.y, w.y, acc[rr]);
            acc[rr] = fmaf(x.z, w.z, acc[rr]);
            acc[rr] = fmaf(x.w, w.w, acc[rr]);
        }
    }
    float gwj = Gw[j], bwj = Bw[j];
    #pragma unroll
    for (int rr = 0; rr < 4; ++rr) {
        int r = rg * 4 + rr;
        float y = rsh[r] * (acc[rr] - msh[r] * gwj) + bwj;
        size_t grow = (size_t)blockIdx.x * ZROWS + r;
        Yz[grow * CP + j] = y;
    }
}

// --- cl_out[a,c] = cl[a,c] + Ys[tok[a],c] ---
__global__ void cl_final_kernel(const float* __restrict__ cl,
                                const float* __restrict__ Ys,
                                const int* __restrict__ tok,
                                float* __restrict__ out) {
    int i = blockIdx.x * blockDim.x + threadIdx.x;  // 0 .. A_N*CA
    int a = i >> 7;
    int c = i & 127;
    out[i] = cl[i] + Ys[tok[a] * CA + c];
}

// --- plm_out[a,b,:] = plm[a,b,:] + Yz[tok[a],tok[b],:]  (float4-vectorized) ---
__global__ void plm_final_kernel(const float* __restrict__ plm,
                                 const float* __restrict__ Yz,
                                 const int* __restrict__ tok,
                                 float* __restrict__ out) {
    int i = blockIdx.x * blockDim.x + threadIdx.x;  // float4 index, 0 .. 4M
    int p  = i >> 2;       // pair index a*1024+b
    int c4 = i & 3;        // which float4 within the 16 channels
    int a = p >> 10;
    int b = p & 1023;
    int ta = tok[a];
    int tb = tok[b];
    float4 pv = ((const float4*)plm)[i];
    float4 yv = ((const float4*)(Yz + (size_t)(ta * T_N + tb) * CP))[c4];
    float4 o;
    o.x = pv.x + yv.x; o.y = pv.y + yv.y;
    o.z = pv.z + yv.z; o.w = pv.w + yv.w;
    ((float4*)out)[i] = o;
}

// --- ql_out[a,c] = ql[a,c] + rl[a,:] @ W_r[:,c] ---
__global__ void ql_final_kernel(const float* __restrict__ ql,
                                const float* __restrict__ rl,
                                const float* __restrict__ W_r,
                                float* __restrict__ out) {
    int i = blockIdx.x * blockDim.x + threadIdx.x;  // 0 .. A_N*CA
    int a = i >> 7;
    int c = i & 127;
    float r0 = rl[a * 3 + 0], r1 = rl[a * 3 + 1], r2 = rl[a * 3 + 2];
    out[i] = ql[i] + r0 * W_r[c] + r1 * W_r[CA + c] + r2 * W_r[2 * CA + c];
}

extern "C" void kernel_launch(void* const* d_in, const int* in_sizes, int n_in,
                              void* d_out, int out_size, void* d_ws, size_t ws_size,
                              hipStream_t stream) {
    const float* a2t     = (const float*)d_in[0];
    const float* cl      = (const float*)d_in[1];
    const float* plm     = (const float*)d_in[2];
    const float* ql      = (const float*)d_in[3];
    const float* s_trunk = (const float*)d_in[4];
    const float* zij     = (const float*)d_in[5];
    const float* rl      = (const float*)d_in[6];
    const float* ln_s_g  = (const float*)d_in[7];
    const float* ln_s_b  = (const float*)d_in[8];
    const float* W_s     = (const float*)d_in[9];
    const float* ln_z_g  = (const float*)d_in[10];
    const float* ln_z_b  = (const float*)d_in[11];
    const float* W_z     = (const float*)d_in[12];
    const float* W_r     = (const float*)d_in[13];

    // workspace layout
    int*   tok = (int*)d_ws;                                    // 1024 ints (4 KB)
    float* Ys  = (float*)((char*)d_ws + 4096);                  // 256*128 floats
    float* Yz  = (float*)((char*)d_ws + 4096 + 131072 * 4);     // 65536*16 floats (4 MB)
    float* Gw  = Yz + (size_t)T_N * T_N * CP;                   // 16 floats
    float* Bw  = Gw + 16;                                       // 16 floats

    // output layout: cl [1024*128], plm [1024*1024*16], ql [1024*128]
    float* out_cl  = (float*)d_out;
    float* out_plm = out_cl + A_N * CA;
    float* out_ql  = out_plm + (size_t)A_N * A_N * CP;

    tok_kernel<<<A_N, T_N, 0, stream>>>(a2t, tok);
    prep_gwbw_kernel<<<1, 256, 0, stream>>>(ln_z_g, ln_z_b, W_z, Gw, Bw);
    s_phase_kernel<<<T_N, 128, 0, stream>>>(s_trunk, ln_s_g, ln_s_b, W_s, Ys);
    z_phase2_kernel<<<(T_N * T_N) / ZROWS, 256, 0, stream>>>(zij, ln_z_g, W_z, Gw, Bw, Yz);
    cl_final_kernel<<<(A_N * CA) / 256, 256, 0, stream>>>(cl, Ys, tok, out_cl);
    plm_final_kernel<<<((size_t)A_N * A_N * CP / 4) / 256, 256, 0, stream>>>(plm, Yz, tok, out_plm);
    ql_final_kernel<<<(A_N * CA) / 256, 256, 0, stream>>>(ql, rl, W_r, out_ql);
}

// Round 3
// 200.927 us; speedup vs baseline: 1.2931x; 1.0250x over previous
//
#include <hip/hip_runtime.h>

#define A_N 1024
#define T_N 256
#define CS 384
#define CZ 128
#define CA 128
#define CP 16
#define LN_EPS 1e-5f

#define ZROWS 64     // rows per z-phase block
#define ZPAD 132     // padded LDS row stride (floats), 16B-aligned, breaks bank aliasing

// ============================================================================
// Kernel 1: per-atom fused — tok recovery + LN(s_trunk[tok])@W_s + cl add + ql
// One block per atom, 128 threads (= c_atom outputs).
// ============================================================================
__global__ __launch_bounds__(128) void atom_kernel(
        const float* __restrict__ a2t,
        const float* __restrict__ cl,
        const float* __restrict__ ql,
        const float* __restrict__ s_trunk,
        const float* __restrict__ rl,
        const float* __restrict__ g,
        const float* __restrict__ b,
        const float* __restrict__ W_s,
        const float* __restrict__ W_r,
        int* __restrict__ tok,
        float* __restrict__ out_cl,
        float* __restrict__ out_ql) {
    int a = blockIdx.x, tid = threadIdx.x;
    __shared__ int ta_sh;
    __shared__ float xs[CS];
    __shared__ float2 wred[2];

    // recover token index from one-hot row (exactly one element > 0.5)
    float v0 = a2t[a * T_N + tid];
    float v1 = a2t[a * T_N + 128 + tid];
    if (v0 > 0.5f) ta_sh = tid;
    if (v1 > 0.5f) ta_sh = 128 + tid;
    __syncthreads();
    int ta = ta_sh;
    if (tid == 0) tok[a] = ta;

    // load s_trunk[ta,:] and compute LN stats
    float sum = 0.f, sq = 0.f;
    #pragma unroll
    for (int j = 0; j < 3; ++j) {
        float v = s_trunk[ta * CS + j * 128 + tid];
        xs[j * 128 + tid] = v;
        sum += v; sq += v * v;
    }
    #pragma unroll
    for (int off = 32; off > 0; off >>= 1) {
        sum += __shfl_down(sum, off);
        sq  += __shfl_down(sq,  off);
    }
    if ((tid & 63) == 0) wred[tid >> 6] = make_float2(sum, sq);
    __syncthreads();
    float s  = wred[0].x + wred[1].x;
    float ss = wred[0].y + wred[1].y;
    float m = s * (1.f / CS);
    float rstd = rsqrtf(ss * (1.f / CS) - m * m + LN_EPS);

    // out_cl[a,tid] = cl[a,tid] + LN(x) @ W_s[:,tid]
    float acc = 0.f;
    for (int k = 0; k < CS; ++k) {
        float zn = (xs[k] - m) * rstd * g[k] + b[k];   // k-uniform g,b -> scalar loads
        acc = fmaf(zn, W_s[k * CA + tid], acc);
    }
    out_cl[a * CA + tid] = cl[a * CA + tid] + acc;

    // out_ql[a,tid] = ql[a,tid] + rl[a,:] @ W_r[:,tid]
    float r0 = rl[a * 3 + 0], r1 = rl[a * 3 + 1], r2 = rl[a * 3 + 2];
    out_ql[a * CA + tid] = ql[a * CA + tid]
                         + r0 * W_r[tid] + r1 * W_r[CA + tid] + r2 * W_r[2 * CA + tid];
}

// ============================================================================
// Kernel 2: Yz[row,:] = LN(zij[row,:]) @ W_z, 64 rows per 256-thread block.
// LN folded into matmul: y[j] = rstd*(x@(g*W)[:,j] - m*Gw[j]) + Bw[j],
// with Gw/Bw computed in-block from the staged W tile.
// ============================================================================
__global__ __launch_bounds__(256) void z_kernel(
        const float* __restrict__ zij,
        const float* __restrict__ g,
        const float* __restrict__ b,
        const float* __restrict__ W_z,
        float* __restrict__ Yz) {
    __shared__ float xs[ZROWS * ZPAD];       // 64 x 128 tile, padded
    __shared__ float wgt[CP * ZPAD];         // wgt[j][k] = g[k]*W[k][j]
    __shared__ float2 parts[ZROWS][4];       // per-row partial (sum, sumsq)
    __shared__ float msh[ZROWS], rsh[ZROWS];
    __shared__ float2 gb_part[16][16];
    __shared__ float Gw_sh[CP], Bw_sh[CP];

    int t = threadIdx.x;
    size_t base = (size_t)blockIdx.x * ZROWS * CZ;

    // stage x tile: 64 rows x 32 float4, coalesced
    const float4* zv = (const float4*)(zij + base);
    #pragma unroll
    for (int n = 0; n < 8; ++n) {
        int idx = n * 256 + t;
        int r = idx >> 5, c = idx & 31;
        *(float4*)&xs[r * ZPAD + c * 4] = zv[idx];
    }
    // stage Wg transposed + Gw/Bw partials
    {
        int j = t & 15, seg = t >> 4;        // 16 segs x 8 k's
        float sg = 0.f, sb = 0.f;
        #pragma unroll
        for (int i = 0; i < 8; ++i) {
            int k = seg * 8 + i;
            float w = W_z[k * CP + j];
            float gw = g[k] * w;
            wgt[j * ZPAD + k] = gw;
            sg += gw;
            sb = fmaf(b[k], w, sb);
        }
        gb_part[seg][j] = make_float2(sg, sb);
    }
    __syncthreads();
    if (t < CP) {
        float sg = 0.f, sb = 0.f;
        #pragma unroll
        for (int s = 0; s < 16; ++s) { float2 p = gb_part[s][t]; sg += p.x; sb += p.y; }
        Gw_sh[t] = sg; Bw_sh[t] = sb;
    }
    // per-row stats: 4 threads per row, 32 elements each
    {
        int r = t >> 2, q = t & 3;
        const float* row = &xs[r * ZPAD + q * 32];
        float s = 0.f, ss = 0.f;
        #pragma unroll
        for (int i = 0; i < 8; ++i) {
            float4 v = *(const float4*)&row[i * 4];
            s += v.x + v.y + v.z + v.w;
            ss += v.x * v.x + v.y * v.y + v.z * v.z + v.w * v.w;
        }
        parts[r][q] = make_float2(s, ss);
    }
    __syncthreads();
    if (t < ZROWS) {
        float s = 0.f, ss = 0.f;
        #pragma unroll
        for (int q = 0; q < 4; ++q) { float2 p = parts[t][q]; s += p.x; ss += p.y; }
        float m = s * (1.f / CZ);
        msh[t] = m;
        rsh[t] = rsqrtf(ss * (1.f / CZ) - m * m + LN_EPS);
    }
    __syncthreads();

    // matmul: thread (rg, j) computes 4 rows x 1 output
    int j = t & 15, rg = t >> 4;
    float acc[4] = {0.f, 0.f, 0.f, 0.f};
    const float* wrow = &wgt[j * ZPAD];
    #pragma unroll 4
    for (int k4 = 0; k4 < 32; ++k4) {
        float4 w = *(const float4*)&wrow[k4 * 4];
        #pragma unroll
        for (int rr = 0; rr < 4; ++rr) {
            float4 x = *(const float4*)&xs[(rg * 4 + rr) * ZPAD + k4 * 4];
            acc[rr] = fmaf(x.x, w.x, acc[rr]);
            acc[rr] = fmaf(x.y, w.y, acc[rr]);
            acc[rr] = fmaf(x.z, w.z, acc[rr]);
            acc[rr] = fmaf(x.w, w.w, acc[rr]);
        }
    }
    float gwj = Gw_sh[j], bwj = Bw_sh[j];
    #pragma unroll
    for (int rr = 0; rr < 4; ++rr) {
        int r = rg * 4 + rr;
        float y = rsh[r] * (acc[rr] - msh[r] * gwj) + bwj;
        size_t grow = (size_t)blockIdx.x * ZROWS + r;
        Yz[grow * CP + j] = y;
    }
}

// ============================================================================
// Kernel 3: plm_out[a,b,:] = plm[a,b,:] + Yz[tok[a],tok[b],:]
// float4 per thread; `a` is block-uniform (256 float4 = 64 pairs per block).
// ============================================================================
__global__ __launch_bounds__(256) void plm_kernel(
        const float* __restrict__ plm,
        const float* __restrict__ Yz,
        const int* __restrict__ tok,
        float* __restrict__ out) {
    int tid = threadIdx.x;
    size_t i = (size_t)blockIdx.x * 256 + tid;     // float4 index
    int ta = tok[blockIdx.x >> 4];                 // a = blockIdx/16, block-uniform
    int bb = ((blockIdx.x & 15) << 6) + (tid >> 2);
    int tb = tok[bb];
    float4 pv = ((const float4*)plm)[i];
    float4 yv = ((const float4*)(Yz + (size_t)(ta * T_N + tb) * CP))[tid & 3];
    float4 o;
    o.x = pv.x + yv.x; o.y = pv.y + yv.y;
    o.z = pv.z + yv.z; o.w = pv.w + yv.w;
    ((float4*)out)[i] = o;
}

extern "C" void kernel_launch(void* const* d_in, const int* in_sizes, int n_in,
                              void* d_out, int out_size, void* d_ws, size_t ws_size,
                              hipStream_t stream) {
    const float* a2t     = (const float*)d_in[0];
    const float* cl      = (const float*)d_in[1];
    const float* plm     = (const float*)d_in[2];
    const float* ql      = (const float*)d_in[3];
    const float* s_trunk = (const float*)d_in[4];
    const float* zij     = (const float*)d_in[5];
    const float* rl      = (const float*)d_in[6];
    const float* ln_s_g  = (const float*)d_in[7];
    const float* ln_s_b  = (const float*)d_in[8];
    const float* W_s     = (const float*)d_in[9];
    const float* ln_z_g  = (const float*)d_in[10];
    const float* ln_z_b  = (const float*)d_in[11];
    const float* W_z     = (const float*)d_in[12];
    const float* W_r     = (const float*)d_in[13];

    // workspace layout
    int*   tok = (int*)d_ws;                       // 1024 ints (4 KB)
    float* Yz  = (float*)((char*)d_ws + 4096);     // 65536*16 floats (4 MB)

    // output layout: cl [1024*128], plm [1024*1024*16], ql [1024*128]
    float* out_cl  = (float*)d_out;
    float* out_plm = out_cl + A_N * CA;
    float* out_ql  = out_plm + (size_t)A_N * A_N * CP;

    atom_kernel<<<A_N, 128, 0, stream>>>(a2t, cl, ql, s_trunk, rl,
                                         ln_s_g, ln_s_b, W_s, W_r,
                                         tok, out_cl, out_ql);
    z_kernel<<<(T_N * T_N) / ZROWS, 256, 0, stream>>>(zij, ln_z_g, ln_z_b, W_z, Yz);
    plm_kernel<<<((size_t)A_N * A_N * CP / 4) / 256, 256, 0, stream>>>(plm, Yz, tok, out_plm);
}

// Round 4
// 191.876 us; speedup vs baseline: 1.3541x; 1.0472x over previous
//
#include <hip/hip_runtime.h>

#define A_N 1024
#define T_N 256
#define CS 384
#define CZ 128
#define CA 128
#define CP 16
#define LN_EPS 1e-5f

typedef __bf16  bf16x8 __attribute__((ext_vector_type(8)));
typedef float   f32x4  __attribute__((ext_vector_type(4)));

// ============================================================================
// Kernel 1: token-space s phase — Ys[t,:] = LN(s_trunk[t,:]) @ W_s
// 256 blocks x 128 threads; 4-way unrolled k-loop to break the FMA chain.
// ============================================================================
__global__ __launch_bounds__(128) void s_kernel(
        const float* __restrict__ s_trunk,
        const float* __restrict__ g,
        const float* __restrict__ b,
        const float* __restrict__ W_s,
        float* __restrict__ Ys) {
    int t = blockIdx.x, tid = threadIdx.x;
    __shared__ float xs[CS];
    __shared__ float2 wred[2];
    float sum = 0.f, sq = 0.f;
    #pragma unroll
    for (int j = 0; j < 3; ++j) {
        float v = s_trunk[t * CS + j * 128 + tid];
        xs[j * 128 + tid] = v;
        sum += v; sq += v * v;
    }
    #pragma unroll
    for (int off = 32; off > 0; off >>= 1) {
        sum += __shfl_down(sum, off);
        sq  += __shfl_down(sq,  off);
    }
    if ((tid & 63) == 0) wred[tid >> 6] = make_float2(sum, sq);
    __syncthreads();
    float s  = wred[0].x + wred[1].x;
    float ss = wred[0].y + wred[1].y;
    float m = s * (1.f / CS);
    float rstd = rsqrtf(ss * (1.f / CS) - m * m + LN_EPS);

    float a0 = 0.f, a1 = 0.f, a2 = 0.f, a3 = 0.f;
    for (int k = 0; k < CS; k += 4) {
        float z0 = (xs[k + 0] - m) * rstd * g[k + 0] + b[k + 0];
        float z1 = (xs[k + 1] - m) * rstd * g[k + 1] + b[k + 1];
        float z2 = (xs[k + 2] - m) * rstd * g[k + 2] + b[k + 2];
        float z3 = (xs[k + 3] - m) * rstd * g[k + 3] + b[k + 3];
        a0 = fmaf(z0, W_s[(k + 0) * CA + tid], a0);
        a1 = fmaf(z1, W_s[(k + 1) * CA + tid], a1);
        a2 = fmaf(z2, W_s[(k + 2) * CA + tid], a2);
        a3 = fmaf(z3, W_s[(k + 3) * CA + tid], a3);
    }
    Ys[t * CA + tid] = (a0 + a1) + (a2 + a3);
}

// ============================================================================
// Kernel 2: z phase via MFMA. 1024 blocks x 256 threads; each wave owns a
// 16-row M-tile. X is loaded global->registers directly in A-fragment layout
// (no LDS for X); LN stats via cross-quad shuffles; LN folded into epilogue:
//   y[j] = rstd*(x @ (g*W)[:,j] - m*Gw[j]) + Bw[j]
// ============================================================================
#define WSTRIDE 136   // bf16 elements per wb row (272 B, 16B-aligned)

__global__ __launch_bounds__(256) void z_mfma_kernel(
        const float* __restrict__ zij,
        const float* __restrict__ g,
        const float* __restrict__ b,
        const float* __restrict__ W_z,
        float* __restrict__ Yz) {
    __shared__ __bf16 wb[CP * WSTRIDE];     // wb[j][k] = bf16(g[k]*W[k][j])
    __shared__ float2 gb_part[16][16];
    __shared__ float Gw_sh[CP], Bw_sh[CP];

    int t = threadIdx.x;

    // --- stage Wg^T (bf16) + Gw/Bw partials ---
    {
        int j = t & 15, seg = t >> 4;       // 16 segs x 8 k's
        float sg = 0.f, sb = 0.f;
        #pragma unroll
        for (int i = 0; i < 8; ++i) {
            int k = seg * 8 + i;
            float w = W_z[k * CP + j];
            float gw = g[k] * w;
            wb[j * WSTRIDE + k] = (__bf16)gw;
            sg += gw;
            sb = fmaf(b[k], w, sb);
        }
        gb_part[seg][j] = make_float2(sg, sb);
    }
    __syncthreads();
    if (t < CP) {
        float sg = 0.f, sb = 0.f;
        #pragma unroll
        for (int s = 0; s < 16; ++s) { float2 p = gb_part[s][t]; sg += p.x; sb += p.y; }
        Gw_sh[t] = sg; Bw_sh[t] = sb;
    }

    int wave = t >> 6, lane = t & 63;
    int m    = lane & 15, quad = lane >> 4;
    size_t grow = (size_t)blockIdx.x * 64 + wave * 16 + m;   // A-row this lane loads

    // --- load X tile rows straight into registers (A-frag pattern) ---
    // lane covers cols quad*8 + 32s .. +7 for s=0..3  (full row across quads)
    const float4* zrow = (const float4*)(zij + grow * CZ);
    float4 xv[8];
    #pragma unroll
    for (int s = 0; s < 4; ++s) {
        xv[2 * s]     = zrow[quad * 2 + 8 * s];
        xv[2 * s + 1] = zrow[quad * 2 + 8 * s + 1];
    }

    // --- LN stats for row m: per-lane partial over 32 elems, reduce across quads ---
    float sum = 0.f, sq = 0.f;
    #pragma unroll
    for (int i = 0; i < 8; ++i) {
        float4 v = xv[i];
        sum += (v.x + v.y) + (v.z + v.w);
        sq  += v.x * v.x + v.y * v.y + v.z * v.z + v.w * v.w;
    }
    sum += __shfl_xor(sum, 16);  sq += __shfl_xor(sq, 16);
    sum += __shfl_xor(sum, 32);  sq += __shfl_xor(sq, 32);
    float mval = sum * (1.f / CZ);
    float rstd = rsqrtf(sq * (1.f / CZ) - mval * mval + LN_EPS);

    __syncthreads();   // wb/Gw/Bw ready

    // --- MFMA over 4 K-steps ---
    f32x4 acc = {0.f, 0.f, 0.f, 0.f};
    #pragma unroll
    for (int s = 0; s < 4; ++s) {
        float4 v0 = xv[2 * s], v1 = xv[2 * s + 1];
        bf16x8 af;
        af[0] = (__bf16)v0.x; af[1] = (__bf16)v0.y;
        af[2] = (__bf16)v0.z; af[3] = (__bf16)v0.w;
        af[4] = (__bf16)v1.x; af[5] = (__bf16)v1.y;
        af[6] = (__bf16)v1.z; af[7] = (__bf16)v1.w;
        bf16x8 bf = *(const bf16x8*)&wb[m * WSTRIDE + quad * 8 + 32 * s];
        acc = __builtin_amdgcn_mfma_f32_16x16x32_bf16(af, bf, acc, 0, 0, 0);
    }

    // --- epilogue: C layout row = quad*4+i, col = m ---
    float gwj = Gw_sh[m], bwj = Bw_sh[m];
    size_t obase = (size_t)blockIdx.x * 64 + wave * 16;
    #pragma unroll
    for (int i = 0; i < 4; ++i) {
        int r = quad * 4 + i;
        float mi = __shfl(mval, r);     // stats live in lanes 0..15 (lane&15 == row)
        float ri = __shfl(rstd, r);
        float y = ri * (acc[i] - mi * gwj) + bwj;
        Yz[(obase + r) * CP + m] = y;
    }
}

// ============================================================================
// Kernel 3: per-atom — tok recovery + cl add (gather Ys) + ql
// ============================================================================
__global__ __launch_bounds__(128) void atom_kernel(
        const float* __restrict__ a2t,
        const float* __restrict__ cl,
        const float* __restrict__ ql,
        const float* __restrict__ rl,
        const float* __restrict__ Ys,
        const float* __restrict__ W_r,
        int* __restrict__ tok,
        float* __restrict__ out_cl,
        float* __restrict__ out_ql) {
    int a = blockIdx.x, tid = threadIdx.x;
    __shared__ int ta_sh;
    float v0 = a2t[a * T_N + tid];
    float v1 = a2t[a * T_N + 128 + tid];
    if (v0 > 0.5f) ta_sh = tid;
    if (v1 > 0.5f) ta_sh = 128 + tid;
    __syncthreads();
    int ta = ta_sh;
    if (tid == 0) tok[a] = ta;

    out_cl[a * CA + tid] = cl[a * CA + tid] + Ys[ta * CA + tid];

    float r0 = rl[a * 3 + 0], r1 = rl[a * 3 + 1], r2 = rl[a * 3 + 2];
    out_ql[a * CA + tid] = ql[a * CA + tid]
                         + r0 * W_r[tid] + r1 * W_r[CA + tid] + r2 * W_r[2 * CA + tid];
}

// ============================================================================
// Kernel 4: plm_out[a,b,:] = plm[a,b,:] + Yz[tok[a],tok[b],:]
// ============================================================================
__global__ __launch_bounds__(256) void plm_kernel(
        const float* __restrict__ plm,
        const float* __restrict__ Yz,
        const int* __restrict__ tok,
        float* __restrict__ out) {
    int tid = threadIdx.x;
    size_t i = (size_t)blockIdx.x * 256 + tid;     // float4 index
    int ta = tok[blockIdx.x >> 4];                 // a block-uniform
    int bb = ((blockIdx.x & 15) << 6) + (tid >> 2);
    int tb = tok[bb];
    float4 pv = ((const float4*)plm)[i];
    float4 yv = ((const float4*)(Yz + (size_t)(ta * T_N + tb) * CP))[tid & 3];
    float4 o;
    o.x = pv.x + yv.x; o.y = pv.y + yv.y;
    o.z = pv.z + yv.z; o.w = pv.w + yv.w;
    ((float4*)out)[i] = o;
}

extern "C" void kernel_launch(void* const* d_in, const int* in_sizes, int n_in,
                              void* d_out, int out_size, void* d_ws, size_t ws_size,
                              hipStream_t stream) {
    const float* a2t     = (const float*)d_in[0];
    const float* cl      = (const float*)d_in[1];
    const float* plm     = (const float*)d_in[2];
    const float* ql      = (const float*)d_in[3];
    const float* s_trunk = (const float*)d_in[4];
    const float* zij     = (const float*)d_in[5];
    const float* rl      = (const float*)d_in[6];
    const float* ln_s_g  = (const float*)d_in[7];
    const float* ln_s_b  = (const float*)d_in[8];
    const float* W_s     = (const float*)d_in[9];
    const float* ln_z_g  = (const float*)d_in[10];
    const float* ln_z_b  = (const float*)d_in[11];
    const float* W_z     = (const float*)d_in[12];
    const float* W_r     = (const float*)d_in[13];

    // workspace layout
    int*   tok = (int*)d_ws;                           // 4 KB
    float* Ys  = (float*)((char*)d_ws + 4096);         // 256*128 floats (128 KB)
    float* Yz  = (float*)((char*)d_ws + 4096 + 131072);// 65536*16 floats (4 MB)

    // output layout: cl [1024*128], plm [1024*1024*16], ql [1024*128]
    float* out_cl  = (float*)d_out;
    float* out_plm = out_cl + A_N * CA;
    float* out_ql  = out_plm + (size_t)A_N * A_N * CP;

    s_kernel<<<T_N, 128, 0, stream>>>(s_trunk, ln_s_g, ln_s_b, W_s, Ys);
    z_mfma_kernel<<<(T_N * T_N) / 64, 256, 0, stream>>>(zij, ln_z_g, ln_z_b, W_z, Yz);
    atom_kernel<<<A_N, 128, 0, stream>>>(a2t, cl, ql, rl, Ys, W_r, tok, out_cl, out_ql);
    plm_kernel<<<((size_t)A_N * A_N * CP / 4) / 256, 256, 0, stream>>>(plm, Yz, tok, out_plm);
}